// Round 1
// baseline (796.684 us; speedup 1.0000x reference)
//
#include <hip/hip_runtime.h>

#define BATCH  16
#define NPRED  25200
#define NCLS   80
#define CDIM   85
#define TOPK   4096
#define NPAD   28672   // 7 * 4096
#define NCHUNK 7
#define MAXDET 1000
#define CONF_T 0.25f
#define IOU_T  0.45f
#define MAXWH  7680.0f

typedef unsigned long long u64;
typedef unsigned int u32;

// ---------------- bitonic helpers (blockDim.x == 1024, n == 4096) ----------------

__device__ __forceinline__ void sort4096_desc_u64(u64* a) {
    const int tid = threadIdx.x;
    for (int k = 2; k <= 4096; k <<= 1) {
        for (int j = k >> 1; j > 0; j >>= 1) {
            __syncthreads();
#pragma unroll
            for (int t = 0; t < 4; ++t) {
                int i = (t << 10) | tid;
                int p = i ^ j;
                if (p > i) {
                    u64 x = a[i], y = a[p];
                    bool desc = ((i & k) == 0);
                    if (desc ? (x < y) : (x > y)) { a[i] = y; a[p] = x; }
                }
            }
        }
    }
    __syncthreads();
}

__device__ __forceinline__ void merge4096_desc_u64(u64* a) {
    const int tid = threadIdx.x;
    for (int j = 2048; j > 0; j >>= 1) {
        __syncthreads();
#pragma unroll
        for (int t = 0; t < 4; ++t) {
            int i = (t << 10) | tid;
            int p = i ^ j;
            if (p > i) {
                u64 x = a[i], y = a[p];
                if (x < y) { a[i] = y; a[p] = x; }
            }
        }
    }
    __syncthreads();
}

__device__ __forceinline__ void sort4096_asc_u32(u32* a) {
    const int tid = threadIdx.x;
    for (int k = 2; k <= 4096; k <<= 1) {
        for (int j = k >> 1; j > 0; j >>= 1) {
            __syncthreads();
#pragma unroll
            for (int t = 0; t < 4; ++t) {
                int i = (t << 10) | tid;
                int p = i ^ j;
                if (p > i) {
                    u32 x = a[i], y = a[p];
                    bool asc = ((i & k) == 0);
                    if (asc ? (x > y) : (x < y)) { a[i] = y; a[p] = x; }
                }
            }
        }
    }
    __syncthreads();
}

// ---------------- K1: score / argmax / key ----------------
// key = ord(score)<<32 | (NPAD-1-n)<<7 | cls   (desc sort == stable argsort(-s))

__global__ void k1_score(const float* __restrict__ pred, u64* __restrict__ keys) {
    int idx = blockIdx.x * blockDim.x + threadIdx.x;   // grid covers BATCH*NPAD exactly
    int b = idx / NPAD;
    int n = idx - b * NPAD;
    u64 key = 0ull;
    if (n < NPRED) {
        const float* row = pred + ((long long)b * NPRED + n) * CDIM;
        float obj = row[4];
        float best = -1.0f;
        int bi = 0;
        for (int j = 0; j < NCLS; ++j) {
            float v = row[5 + j] * obj;          // reference order: product then max
            if (v > best) { best = v; bi = j; }  // strict '>' keeps first max (jnp.argmax)
        }
        float s = (best > CONF_T) ? best : -1.0f;
        u32 u = __float_as_uint(s);
        u32 ord = (u & 0x80000000u) ? ~u : (u | 0x80000000u);
        key = ((u64)ord << 32) | ((u64)(u32)(NPAD - 1 - n) << 7) | (u64)(u32)bi;
    }
    keys[idx] = key;
}

// ---------------- K2: per-batch top-4096 (chunked bitonic sort + merge) ----------------

__global__ __launch_bounds__(1024) void k2_topk(u64* __restrict__ keys) {
    __shared__ u64 top[4096];
    __shared__ u64 buf[4096];
    const int b = blockIdx.x;
    const int tid = threadIdx.x;
    u64* kb = keys + (long long)b * NPAD;

#pragma unroll
    for (int t = 0; t < 4; ++t) { int i = (t << 10) | tid; top[i] = kb[i]; }
    sort4096_desc_u64(top);

    for (int c = 1; c < NCHUNK; ++c) {
#pragma unroll
        for (int t = 0; t < 4; ++t) { int i = (t << 10) | tid; buf[i] = kb[c * 4096 + i]; }
        sort4096_desc_u64(buf);
        // elementwise max of top[i] vs buf[4095-i] -> bitonic sequence holding top-4096 of union
#pragma unroll
        for (int t = 0; t < 4; ++t) {
            int i = (t << 10) | tid;
            u64 x = top[i], y = buf[4095 - i];
            top[i] = (x > y) ? x : y;
        }
        merge4096_desc_u64(top);
    }
#pragma unroll
    for (int t = 0; t < 4; ++t) { int i = (t << 10) | tid; kb[i] = top[i]; }
}

// ---------------- K3: class bucketing + per-class greedy NMS + compaction ----------------

__global__ __launch_bounds__(1024) void k3_nms(const float* __restrict__ pred,
                                               const u64* __restrict__ keys,
                                               float4* __restrict__ ob,
                                               float* __restrict__ out) {
    const int b = blockIdx.x;
    const int tid = threadIdx.x;
    __shared__ u32 ckey[TOPK];
    __shared__ unsigned char supp[TOPK];
    __shared__ unsigned char keep[TOPK];
    __shared__ int segStart[NCLS];
    __shared__ int segEnd[NCLS];
    __shared__ u64 words[TOPK / 64];
    __shared__ int wpre[TOPK / 64];

    float* outb = out + (long long)b * MAXDET * 6;
    for (int i = tid; i < MAXDET * 6; i += 1024) outb[i] = 0.0f;  // d_out is poisoned
    if (tid < NCLS) { segStart[tid] = -1; segEnd[tid] = 0; }

    const u64* kb = keys + (long long)b * NPAD;
#pragma unroll
    for (int t = 0; t < 4; ++t) {
        int r = (t << 10) | tid;
        u64 key = kb[r];
        u32 hi = (u32)(key >> 32);
        u32 c = 128u;                      // invalid sentinel -> sorts after real classes
        if (hi > 0x80000000u) {            // score > 0 (valid candidate)
            int n = (NPAD - 1) - (int)((key >> 7) & 0x7FFFu);
            int ci = (int)(key & 0x7Fu);
            const float* row = pred + ((long long)b * NPRED + n) * CDIM;
            float x = row[0], y = row[1], w = row[2], h = row[3];
            float off = (float)ci * MAXWH;
            float4 o;
            o.x = (x - w * 0.5f) + off;
            o.y = (y - h * 0.5f) + off;
            o.z = (x + w * 0.5f) + off;
            o.w = (y + h * 0.5f) + off;
            ob[b * TOPK + r] = o;
            c = (u32)ci;
        }
        ckey[r] = (c << 12) | (u32)r;
        supp[r] = 0;
        keep[r] = 0;
    }

    sort4096_asc_u32(ckey);   // groups by class, rank order preserved within class

#pragma unroll
    for (int t = 0; t < 4; ++t) {
        int q = (t << 10) | tid;
        u32 c = ckey[q] >> 12;
        if (c < NCLS) {
            if (q == 0 || (ckey[q - 1] >> 12) != c) segStart[c] = q;
            if (q == TOPK - 1 || (ckey[q + 1] >> 12) != c) segEnd[c] = q + 1;
        }
    }
    __syncthreads();

    // greedy NMS: one wave per class (cross-class IoU is exactly 0 due to class offset)
    {
#pragma clang fp contract(off)
        const int wave = tid >> 6;
        const int lane = tid & 63;
        const float4* obb = ob + b * TOPK;
        for (int c = wave; c < NCLS; c += 16) {
            int s0 = segStart[c];
            if (s0 < 0) continue;
            int e = segEnd[c];
            for (int ii = s0; ii < e; ++ii) {
                int ri = ckey[ii] & 0xFFF;
                if (supp[ri]) continue;     // uniform across wave
                keep[ri] = 1;
                float4 bi = obb[ri];
                float a1 = (bi.z - bi.x) * (bi.w - bi.y);
                for (int jj = ii + 1 + lane; jj < e; jj += 64) {
                    int rj = ckey[jj] & 0xFFF;
                    float4 bj = obb[rj];
                    float ltx = fmaxf(bi.x, bj.x);
                    float lty = fmaxf(bi.y, bj.y);
                    float rbx = fminf(bi.z, bj.z);
                    float rby = fminf(bi.w, bj.w);
                    float ww = fmaxf(rbx - ltx, 0.0f);
                    float hh = fmaxf(rby - lty, 0.0f);
                    float inter = ww * hh;
                    float a2 = (bj.z - bj.x) * (bj.w - bj.y);
                    float iou = inter / (((a1 + a2) - inter) + 1e-7f);
                    if (iou > IOU_T) supp[rj] = 1;
                }
            }
        }
    }
    __syncthreads();

    // compact kept entries in rank order (== stable argsort(-fs))
    if (tid < TOPK / 64) {
        u64 w = 0ull;
        int base = tid << 6;
        for (int bb = 0; bb < 64; ++bb)
            if (keep[base + bb]) w |= (1ull << bb);
        words[tid] = w;
    }
    __syncthreads();
    if (tid == 0) {
        int run = 0;
        for (int t = 0; t < TOPK / 64; ++t) { wpre[t] = run; run += __popcll(words[t]); }
    }
    __syncthreads();

#pragma unroll
    for (int t = 0; t < 4; ++t) {
        int r = (t << 10) | tid;
        if (keep[r]) {
            int wd = r >> 6;
            int pos = wpre[wd] + __popcll(words[wd] & ((1ull << (r & 63)) - 1ull));
            if (pos < MAXDET) {
                u64 key = kb[r];
                u32 hi = (u32)(key >> 32);
                int n = (NPAD - 1) - (int)((key >> 7) & 0x7FFFu);
                const float* row = pred + ((long long)b * NPRED + n) * CDIM;
                float x = row[0], y = row[1], w2 = row[2], h = row[3];
                float* o = outb + pos * 6;
                o[0] = x - w2 * 0.5f;
                o[1] = y - h * 0.5f;
                o[2] = x + w2 * 0.5f;
                o[3] = y + h * 0.5f;
                o[4] = __uint_as_float(hi & 0x7FFFFFFFu);   // score
                o[5] = (float)(key & 0x7Fu);                // class (as float)
            }
        }
    }
}

// ---------------- launch ----------------

extern "C" void kernel_launch(void* const* d_in, const int* in_sizes, int n_in,
                              void* d_out, int out_size, void* d_ws, size_t ws_size,
                              hipStream_t stream) {
    const float* pred = (const float*)d_in[0];
    float* out = (float*)d_out;

    u64* keys = (u64*)d_ws;                                           // BATCH*NPAD*8   = 3,670,016 B
    float4* ob = (float4*)((char*)d_ws + (size_t)BATCH * NPAD * 8);   // BATCH*TOPK*16  = 1,048,576 B

    hipLaunchKernelGGL(k1_score, dim3(BATCH * NPAD / 256), dim3(256), 0, stream, pred, keys);
    hipLaunchKernelGGL(k2_topk, dim3(BATCH), dim3(1024), 0, stream, keys);
    hipLaunchKernelGGL(k3_nms, dim3(BATCH), dim3(1024), 0, stream, pred, keys, ob, out);
}

// Round 2
// 493.203 us; speedup vs baseline: 1.6153x; 1.6153x over previous
//
#include <hip/hip_runtime.h>

#define BATCH  16
#define NPRED  25200
#define NCLS   80
#define CDIM   85
#define TOPK   4096
#define NPAD   28672   // 7 * 4096
#define NCHUNK 7
#define MAXDET 1000
#define CONF_T 0.25f
#define IOU_T  0.45f
#define MAXWH  7680.0f

typedef unsigned long long u64;
typedef unsigned int u32;

// ---------------- bitonic helpers ----------------
// pair-index form: 2048 pairs, every lane does useful work.
// i = ((q & ~(j-1)) << 1) | (q & (j-1)); p = i | j.

__device__ __forceinline__ void cx_u64(u64* a, int i, int p, bool desc) {
    u64 x = a[i], y = a[p];
    if (desc ? (x < y) : (x > y)) { a[i] = y; a[p] = x; }
}

// full desc sort of 4096 u64, blockDim.x == 1024
__device__ __forceinline__ void sort4096_desc_u64(u64* a) {
    const int tid = threadIdx.x;
    for (int k = 2; k <= 4096; k <<= 1) {
        for (int j = k >> 1; j > 0; j >>= 1) {
            __syncthreads();
#pragma unroll
            for (int t = 0; t < 2; ++t) {
                int q = (t << 10) | tid;
                int i = ((q & ~(j - 1)) << 1) | (q & (j - 1));
                cx_u64(a, i, i | j, (i & k) == 0);
            }
        }
    }
    __syncthreads();
}

// desc merge of a bitonic 4096 u64 sequence, blockDim.x == 1024
__device__ __forceinline__ void merge4096_desc_u64(u64* a) {
    const int tid = threadIdx.x;
    for (int j = 2048; j > 0; j >>= 1) {
        __syncthreads();
#pragma unroll
        for (int t = 0; t < 2; ++t) {
            int q = (t << 10) | tid;
            int i = ((q & ~(j - 1)) << 1) | (q & (j - 1));
            cx_u64(a, i, i | j, true);
        }
    }
    __syncthreads();
}

// full asc sort of 4096 u32, blockDim.x == 1024
__device__ __forceinline__ void sort4096_asc_u32(u32* a) {
    const int tid = threadIdx.x;
    for (int k = 2; k <= 4096; k <<= 1) {
        for (int j = k >> 1; j > 0; j >>= 1) {
            __syncthreads();
#pragma unroll
            for (int t = 0; t < 2; ++t) {
                int q = (t << 10) | tid;
                int i = ((q & ~(j - 1)) << 1) | (q & (j - 1));
                int p = i | j;
                u32 x = a[i], y = a[p];
                bool asc = ((i & k) == 0);
                if (asc ? (x > y) : (x < y)) { a[i] = y; a[p] = x; }
            }
        }
    }
    __syncthreads();
}

// ---------------- K1: score / argmax / key (wave per row) ----------------
// key = ord(score)<<32 | (NPAD-1-n)<<7 | cls   (desc sort == stable argsort(-s))

__global__ __launch_bounds__(256) void k1_score(const float* __restrict__ pred,
                                                u64* __restrict__ keys) {
    const int lane = threadIdx.x & 63;
    const int gw = blockIdx.x * 4 + (threadIdx.x >> 6);   // global wave id, 4 waves/block
    const int b = gw / NPAD;
    const int n = gw - b * NPAD;
    u64 key = 0ull;
    if (n < NPRED) {
        const float* row = pred + ((long long)b * NPRED + n) * CDIM;
        float obj = row[4];
        // lane j handles class j (and j+64 for j<16); pack (79-cls) so ties pick smaller cls
        float v0 = row[5 + lane] * obj;
        u64 m = ((u64)(__float_as_uint(v0) | 0x80000000u) << 32) | (u64)(u32)(NCLS - 1 - lane);
        if (lane < 16) {
            float v1 = row[69 + lane] * obj;
            u64 m1 = ((u64)(__float_as_uint(v1) | 0x80000000u) << 32) | (u64)(u32)(NCLS - 1 - (64 + lane));
            if (m1 > m) m = m1;
        }
#pragma unroll
        for (int o = 32; o > 0; o >>= 1) {
            u64 other = __shfl_xor(m, o, 64);
            if (other > m) m = other;
        }
        float best = __uint_as_float((u32)(m >> 32) & 0x7FFFFFFFu);
        int cls = (NCLS - 1) - (int)(m & 0x7Fu);
        float s = (best > CONF_T) ? best : -1.0f;
        u32 u = __float_as_uint(s);
        u32 ord = (u & 0x80000000u) ? ~u : (u | 0x80000000u);
        key = ((u64)ord << 32) | ((u64)(u32)(NPAD - 1 - n) << 7) | (u64)(u32)cls;
    }
    if (lane == 0) keys[(long long)b * NPAD + n] = key;
}

// ---------------- K2a: sort each 4096-chunk (one block per batch×chunk) ----------------

__global__ __launch_bounds__(1024) void k2a_sortchunk(u64* __restrict__ keys) {
    __shared__ u64 arr[4096];
    const int tid = threadIdx.x;
    u64* kb = keys + (long long)blockIdx.x * 4096;   // blockIdx.x in [0, BATCH*NCHUNK)
#pragma unroll
    for (int t = 0; t < 4; ++t) { int i = (t << 10) | tid; arr[i] = kb[i]; }
    sort4096_desc_u64(arr);
#pragma unroll
    for (int t = 0; t < 4; ++t) { int i = (t << 10) | tid; kb[i] = arr[i]; }
}

// ---------------- K2m: merge chunk pair (c0, c0+stride) -> c0, keep top-4096 ----------------

__global__ __launch_bounds__(1024) void k2m_merge(u64* __restrict__ keys, int stride) {
    __shared__ u64 arr[4096];
    const int tid = threadIdx.x;
    const int b = blockIdx.x;
    const int c0 = blockIdx.y * 2 * stride;
    const int c1 = c0 + stride;
    const u64* A = keys + (long long)b * NPAD + (long long)c0 * 4096;
    const u64* B = keys + (long long)b * NPAD + (long long)c1 * 4096;
#pragma unroll
    for (int t = 0; t < 4; ++t) {
        int i = (t << 10) | tid;
        u64 x = A[i], y = B[4095 - i];
        arr[i] = (x > y) ? x : y;    // bitonic sequence holding top-4096 of union
    }
    merge4096_desc_u64(arr);
    u64* O = keys + (long long)b * NPAD + (long long)c0 * 4096;
#pragma unroll
    for (int t = 0; t < 4; ++t) { int i = (t << 10) | tid; O[i] = arr[i]; }
}

// ---------------- K3: class bucketing + per-class greedy NMS + compaction ----------------

__global__ __launch_bounds__(1024) void k3_nms(const float* __restrict__ pred,
                                               const u64* __restrict__ keys,
                                               float4* __restrict__ ob,
                                               float* __restrict__ out) {
    const int b = blockIdx.x;
    const int tid = threadIdx.x;
    __shared__ u32 ckey[TOPK];
    __shared__ unsigned char supp[TOPK];
    __shared__ unsigned char keep[TOPK];
    __shared__ int segStart[NCLS];
    __shared__ int segEnd[NCLS];
    __shared__ u64 words[TOPK / 64];
    __shared__ int wpre[TOPK / 64];

    float* outb = out + (long long)b * MAXDET * 6;
    for (int i = tid; i < MAXDET * 6; i += 1024) outb[i] = 0.0f;  // d_out is poisoned
    if (tid < NCLS) { segStart[tid] = -1; segEnd[tid] = 0; }

    const u64* kb = keys + (long long)b * NPAD;   // chunk 0 holds the sorted top-4096
#pragma unroll
    for (int t = 0; t < 4; ++t) {
        int r = (t << 10) | tid;
        u64 key = kb[r];
        u32 hi = (u32)(key >> 32);
        u32 c = 128u;                      // invalid sentinel -> sorts after real classes
        if (hi > 0x80000000u) {            // score > 0 (valid candidate)
            int n = (NPAD - 1) - (int)((key >> 7) & 0x7FFFu);
            int ci = (int)(key & 0x7Fu);
            const float* row = pred + ((long long)b * NPRED + n) * CDIM;
            float x = row[0], y = row[1], w = row[2], h = row[3];
            float off = (float)ci * MAXWH;
            float4 o;
            o.x = (x - w * 0.5f) + off;
            o.y = (y - h * 0.5f) + off;
            o.z = (x + w * 0.5f) + off;
            o.w = (y + h * 0.5f) + off;
            ob[b * TOPK + r] = o;
            c = (u32)ci;
        }
        ckey[r] = (c << 12) | (u32)r;
        supp[r] = 0;
        keep[r] = 0;
    }

    sort4096_asc_u32(ckey);   // groups by class, rank order preserved within class

#pragma unroll
    for (int t = 0; t < 4; ++t) {
        int q = (t << 10) | tid;
        u32 c = ckey[q] >> 12;
        if (c < NCLS) {
            if (q == 0 || (ckey[q - 1] >> 12) != c) segStart[c] = q;
            if (q == TOPK - 1 || (ckey[q + 1] >> 12) != c) segEnd[c] = q + 1;
        }
    }
    __syncthreads();

    // greedy NMS: one wave per class (cross-class IoU is exactly 0 due to class offset)
    {
#pragma clang fp contract(off)
        const int wave = tid >> 6;
        const int lane = tid & 63;
        const float4* obb = ob + b * TOPK;
        for (int c = wave; c < NCLS; c += 16) {
            int s0 = segStart[c];
            if (s0 < 0) continue;
            int e = segEnd[c];
            for (int ii = s0; ii < e; ++ii) {
                int ri = ckey[ii] & 0xFFF;
                if (supp[ri]) continue;     // uniform across wave
                keep[ri] = 1;
                float4 bi = obb[ri];
                float a1 = (bi.z - bi.x) * (bi.w - bi.y);
                for (int jj = ii + 1 + lane; jj < e; jj += 64) {
                    int rj = ckey[jj] & 0xFFF;
                    float4 bj = obb[rj];
                    float ltx = fmaxf(bi.x, bj.x);
                    float lty = fmaxf(bi.y, bj.y);
                    float rbx = fminf(bi.z, bj.z);
                    float rby = fminf(bi.w, bj.w);
                    float ww = fmaxf(rbx - ltx, 0.0f);
                    float hh = fmaxf(rby - lty, 0.0f);
                    float inter = ww * hh;
                    float a2 = (bj.z - bj.x) * (bj.w - bj.y);
                    float iou = inter / (((a1 + a2) - inter) + 1e-7f);
                    if (iou > IOU_T) supp[rj] = 1;
                }
            }
        }
    }
    __syncthreads();

    // compact kept entries in rank order (== stable argsort(-fs))
    if (tid < TOPK / 64) {
        u64 w = 0ull;
        int base = tid << 6;
        for (int bb = 0; bb < 64; ++bb)
            if (keep[base + bb]) w |= (1ull << bb);
        words[tid] = w;
    }
    __syncthreads();
    if (tid == 0) {
        int run = 0;
        for (int t = 0; t < TOPK / 64; ++t) { wpre[t] = run; run += __popcll(words[t]); }
    }
    __syncthreads();

#pragma unroll
    for (int t = 0; t < 4; ++t) {
        int r = (t << 10) | tid;
        if (keep[r]) {
            int wd = r >> 6;
            int pos = wpre[wd] + __popcll(words[wd] & ((1ull << (r & 63)) - 1ull));
            if (pos < MAXDET) {
                u64 key = kb[r];
                u32 hi = (u32)(key >> 32);
                int n = (NPAD - 1) - (int)((key >> 7) & 0x7FFFu);
                const float* row = pred + ((long long)b * NPRED + n) * CDIM;
                float x = row[0], y = row[1], w2 = row[2], h = row[3];
                float* o = outb + pos * 6;
                o[0] = x - w2 * 0.5f;
                o[1] = y - h * 0.5f;
                o[2] = x + w2 * 0.5f;
                o[3] = y + h * 0.5f;
                o[4] = __uint_as_float(hi & 0x7FFFFFFFu);   // score
                o[5] = (float)(key & 0x7Fu);                // class (as float)
            }
        }
    }
}

// ---------------- launch ----------------

extern "C" void kernel_launch(void* const* d_in, const int* in_sizes, int n_in,
                              void* d_out, int out_size, void* d_ws, size_t ws_size,
                              hipStream_t stream) {
    const float* pred = (const float*)d_in[0];
    float* out = (float*)d_out;

    u64* keys = (u64*)d_ws;                                           // BATCH*NPAD*8   = 3,670,016 B
    float4* ob = (float4*)((char*)d_ws + (size_t)BATCH * NPAD * 8);   // BATCH*TOPK*16  = 1,048,576 B

    hipLaunchKernelGGL(k1_score, dim3(BATCH * NPAD / 4), dim3(256), 0, stream, pred, keys);
    hipLaunchKernelGGL(k2a_sortchunk, dim3(BATCH * NCHUNK), dim3(1024), 0, stream, keys);
    hipLaunchKernelGGL(k2m_merge, dim3(BATCH, 3), dim3(1024), 0, stream, keys, 1);
    hipLaunchKernelGGL(k2m_merge, dim3(BATCH, 2), dim3(1024), 0, stream, keys, 2);
    hipLaunchKernelGGL(k2m_merge, dim3(BATCH, 1), dim3(1024), 0, stream, keys, 4);
    hipLaunchKernelGGL(k3_nms, dim3(BATCH), dim3(1024), 0, stream, pred, keys, ob, out);
}

// Round 4
// 315.606 us; speedup vs baseline: 2.5243x; 1.5627x over previous
//
#include <hip/hip_runtime.h>

#define BATCH  16
#define NPRED  25200
#define NCLS   80
#define CDIM   85
#define TOPK   4096
#define NPAD   28672   // 7 * 4096
#define NCHUNK 7
#define MAXDET 1000
#define CONF_T 0.25f
#define IOU_T  0.45f
#define MAXWH  7680.0f

typedef unsigned long long u64;
typedef unsigned int u32;
typedef unsigned short u16;
typedef unsigned char u8;

// ---------------- bitonic helpers (pair-index form, blockDim.x == 1024) ----------------

__device__ __forceinline__ void cx_u64(u64* a, int i, int p, bool desc) {
    u64 x = a[i], y = a[p];
    if (desc ? (x < y) : (x > y)) { a[i] = y; a[p] = x; }
}

__device__ __forceinline__ void sort4096_desc_u64(u64* a) {
    const int tid = threadIdx.x;
    for (int k = 2; k <= 4096; k <<= 1) {
        for (int j = k >> 1; j > 0; j >>= 1) {
            __syncthreads();
#pragma unroll
            for (int t = 0; t < 2; ++t) {
                int q = (t << 10) | tid;
                int i = ((q & ~(j - 1)) << 1) | (q & (j - 1));
                cx_u64(a, i, i | j, (i & k) == 0);
            }
        }
    }
    __syncthreads();
}

__device__ __forceinline__ void merge4096_desc_u64(u64* a) {
    const int tid = threadIdx.x;
    for (int j = 2048; j > 0; j >>= 1) {
        __syncthreads();
#pragma unroll
        for (int t = 0; t < 2; ++t) {
            int q = (t << 10) | tid;
            int i = ((q & ~(j - 1)) << 1) | (q & (j - 1));
            cx_u64(a, i, i | j, true);
        }
    }
    __syncthreads();
}

// ---------------- K1: score / argmax / key (16 lanes per row, 4 rows per wave) ----------------
// key = ord(score)<<32 | (NPAD-1-n)<<7 | cls   (desc sort == stable argsort(-s))

__global__ __launch_bounds__(256) void k1_score(const float* __restrict__ pred,
                                                u64* __restrict__ keys) {
    const int lane = threadIdx.x & 63;
    const int l16 = lane & 15;
    const long long gw = (long long)blockIdx.x * 4 + (threadIdx.x >> 6);
    const long long rowIdx = gw * 4 + (lane >> 4);       // global row in [0, BATCH*NPAD)
    const int b = (int)(rowIdx / NPAD);
    const int n = (int)(rowIdx - (long long)b * NPAD);
    u64 key = 0ull;
    if (n < NPRED) {
        const float* row = pred + ((long long)b * NPRED + n) * CDIM;
        float obj = row[4];
        u64 m = 0ull;
#pragma unroll
        for (int k = 0; k < 5; ++k) {
            int c = l16 + 16 * k;                        // covers 0..79
            float v = row[5 + c] * obj;                  // reference order: product then max
            u64 mk = ((u64)(__float_as_uint(v) | 0x80000000u) << 32) | (u64)(u32)(NCLS - 1 - c);
            if (mk > m) m = mk;                          // (79-c) low bits: ties pick smaller c
        }
#pragma unroll
        for (int o = 8; o > 0; o >>= 1) {
            u64 other = __shfl_xor(m, o, 64);            // reduce within 16-lane group
            if (other > m) m = other;
        }
        float best = __uint_as_float((u32)(m >> 32) & 0x7FFFFFFFu);
        int cls = (NCLS - 1) - (int)(m & 0x7Fu);
        float s = (best > CONF_T) ? best : -1.0f;
        u32 u = __float_as_uint(s);
        u32 ord = (u & 0x80000000u) ? ~u : (u | 0x80000000u);
        key = ((u64)ord << 32) | ((u64)(u32)(NPAD - 1 - n) << 7) | (u64)(u32)cls;
    }
    if (l16 == 0) keys[(long long)b * NPAD + n] = key;   // padding rows write 0
}

// ---------------- K2a: sort each 4096-chunk (one block per batch×chunk) ----------------

__global__ __launch_bounds__(1024) void k2a_sortchunk(u64* __restrict__ keys) {
    __shared__ u64 arr[4096];
    const int tid = threadIdx.x;
    u64* kb = keys + (long long)blockIdx.x * 4096;       // blockIdx.x in [0, BATCH*NCHUNK)
#pragma unroll
    for (int t = 0; t < 4; ++t) { int i = (t << 10) | tid; arr[i] = kb[i]; }
    sort4096_desc_u64(arr);
#pragma unroll
    for (int t = 0; t < 4; ++t) { int i = (t << 10) | tid; kb[i] = arr[i]; }
}

// ---------------- K2m: merge chunk pair (c0, c0+stride) -> c0, keep top-4096 ----------------

__global__ __launch_bounds__(1024) void k2m_merge(u64* __restrict__ keys, int stride) {
    __shared__ u64 arr[4096];
    const int tid = threadIdx.x;
    const int b = blockIdx.x;
    const int c0 = blockIdx.y * 2 * stride;
    const u64* A = keys + (long long)b * NPAD + (long long)c0 * 4096;
    const u64* B = keys + (long long)b * NPAD + (long long)(c0 + stride) * 4096;
#pragma unroll
    for (int t = 0; t < 4; ++t) {
        int i = (t << 10) | tid;
        u64 x = A[i], y = B[4095 - i];
        arr[i] = (x > y) ? x : y;    // bitonic sequence holding top-4096 of union
    }
    merge4096_desc_u64(arr);
    u64* O = keys + (long long)b * NPAD + (long long)c0 * 4096;
#pragma unroll
    for (int t = 0; t < 4; ++t) { int i = (t << 10) | tid; O[i] = arr[i]; }
}

// ---------------- K3a: per-entry class byte + offset-box + class counts ----------------

__global__ __launch_bounds__(256) void k3a_build(const float* __restrict__ pred,
                                                 const u64* __restrict__ keys,
                                                 float4* __restrict__ ob,
                                                 u8* __restrict__ clsb,
                                                 u32* __restrict__ count) {
    const int idx = blockIdx.x * 256 + threadIdx.x;      // 0 .. BATCH*TOPK-1
    const int b = idx >> 12;
    const int r = idx & 4095;
    u64 key = keys[(long long)b * NPAD + r];             // chunk 0 = sorted top-4096
    u32 hi = (u32)(key >> 32);
    u8 c = 0xFF;
    if (hi > 0x80000000u) {                              // score > 0 (valid)
        int n = (NPAD - 1) - (int)((key >> 7) & 0x7FFFu);
        int ci = (int)(key & 0x7Fu);
        const float* row = pred + ((long long)b * NPRED + n) * CDIM;
        float x = row[0], y = row[1], w = row[2], h = row[3];
        float off = (float)ci * MAXWH;
        float4 o;
        o.x = (x - w * 0.5f) + off;
        o.y = (y - h * 0.5f) + off;
        o.z = (x + w * 0.5f) + off;
        o.w = (y + h * 0.5f) + off;
        ob[idx] = o;
        c = (u8)ci;
        atomicAdd(&count[b * NCLS + ci], 1u);
    }
    clsb[idx] = c;
}

// ---------------- K3g: stable per-class index gather (one wave per (b,c)) ----------------

__global__ __launch_bounds__(64) void k3g_gather(const u8* __restrict__ clsb,
                                                 const u32* __restrict__ count,
                                                 u32* __restrict__ startg,
                                                 u16* __restrict__ segIdx) {
    const int b = blockIdx.x;
    const int c = blockIdx.y;
    const int lane = threadIdx.x;
    // start = sum_{c' < c} count[b][c']
    u32 s = (lane < c) ? count[b * NCLS + lane] : 0u;
    if (lane + 64 < c) s += count[b * NCLS + 64 + lane];
#pragma unroll
    for (int o = 32; o > 0; o >>= 1) s += __shfl_xor(s, o, 64);
    if (lane == 0) startg[b * NCLS + c] = s;
    const u32 base = (u32)b * 4096u;
    u32 pos = s;
    const u64 lt = (1ull << lane) - 1ull;
    for (int it = 0; it < 64; ++it) {
        u8 cc = clsb[base + it * 64 + lane];
        u64 m = __ballot(cc == (u8)c);
        if (cc == (u8)c) {
            int ofs = __popcll(m & lt);
            segIdx[base + pos + ofs] = (u16)(it * 64 + lane);
        }
        pos += (u32)__popcll(m);
    }
}

// ---------------- K3n: greedy NMS, one wave per (b,c) ----------------

__global__ __launch_bounds__(64) void k3n_nms(const float4* __restrict__ ob,
                                              const u16* __restrict__ segIdx,
                                              const u32* __restrict__ count,
                                              const u32* __restrict__ startg,
                                              u8* __restrict__ keep,
                                              u8* gsupp_) {
    const int b = blockIdx.x;
    const int c = blockIdx.y;
    const int lane = threadIdx.x;
    const int n = (int)count[b * NCLS + c];
    if (n == 0) return;
    const u32 base = startg[b * NCLS + c];
    __shared__ float4 sbox[1024];
    __shared__ u16 sidx[1024];
    __shared__ u8 ssupp_[1024];
    volatile u8* ssupp = ssupp_;
    volatile u8* gsupp = gsupp_ + b * 4096 + base;       // fallback (n > 1024), pre-zeroed
    const float4* obb = ob + b * 4096;
    const u16* seg = segIdx + b * 4096 + base;

    for (int j = lane; j < n && j < 1024; j += 64) {
        int r = seg[j];
        sidx[j] = (u16)r;
        sbox[j] = obb[r];
        ssupp_[j] = 0;
    }
    __syncthreads();

    {
#pragma clang fp contract(off)
        for (int ii = 0; ii < n; ++ii) {
            bool sup = (ii < 1024) ? (ssupp[ii] != 0) : (gsupp[ii] != 0);
            if (sup) continue;                           // wave-uniform
            int ri = (ii < 1024) ? (int)sidx[ii] : (int)seg[ii];
            if (lane == 0) keep[b * 4096 + ri] = 1;
            float4 bi = (ii < 1024) ? sbox[ii] : obb[seg[ii]];
            float a1 = (bi.z - bi.x) * (bi.w - bi.y);
            for (int jj = ii + 1 + lane; jj < n; jj += 64) {
                float4 bj = (jj < 1024) ? sbox[jj] : obb[seg[jj]];
                float ltx = fmaxf(bi.x, bj.x);
                float lty = fmaxf(bi.y, bj.y);
                float rbx = fminf(bi.z, bj.z);
                float rby = fminf(bi.w, bj.w);
                float ww = fmaxf(rbx - ltx, 0.0f);
                float hh = fmaxf(rby - lty, 0.0f);
                float inter = ww * hh;
                float a2 = (bj.z - bj.x) * (bj.w - bj.y);
                float iou = inter / (((a1 + a2) - inter) + 1e-7f);
                if (iou > IOU_T) {
                    if (jj < 1024) ssupp[jj] = 1; else gsupp[jj] = 1;
                }
            }
            __syncthreads();                             // single-wave: orders LDS supp writes
        }
    }
}

// ---------------- K3o: rank-order compaction + output ----------------

__global__ __launch_bounds__(256) void k3o_out(const float* __restrict__ pred,
                                               const u64* __restrict__ keys,
                                               const u8* __restrict__ keep,
                                               float* __restrict__ out) {
    const int b = blockIdx.x;
    const int tid = threadIdx.x;
    __shared__ u64 words[64];
    __shared__ int wpre[64];
    float* outb = out + (long long)b * MAXDET * 6;
    for (int i = tid; i < MAXDET * 6; i += 256) outb[i] = 0.0f;   // d_out is poisoned
    const u8* kp = keep + b * 4096;
    if (tid < 64) {
        u64 w = 0ull;
        const u64* k8 = (const u64*)(kp + tid * 64);
#pragma unroll
        for (int q = 0; q < 8; ++q) {
            u64 v = k8[q];
#pragma unroll
            for (int bb = 0; bb < 8; ++bb)
                if ((v >> (8 * bb)) & 0xFFull) w |= 1ull << (q * 8 + bb);
        }
        words[tid] = w;
    }
    __syncthreads();
    if (tid == 0) {
        int run = 0;
        for (int t = 0; t < 64; ++t) { wpre[t] = run; run += __popcll(words[t]); }
    }
    __syncthreads();
    const u64* kb = keys + (long long)b * NPAD;
    for (int r = tid; r < 4096; r += 256) {
        int wd = r >> 6;
        if ((words[wd] >> (r & 63)) & 1ull) {
            int pos = wpre[wd] + __popcll(words[wd] & ((1ull << (r & 63)) - 1ull));
            if (pos < MAXDET) {
                u64 key = kb[r];
                u32 hi = (u32)(key >> 32);
                int n = (NPAD - 1) - (int)((key >> 7) & 0x7FFFu);
                const float* row = pred + ((long long)b * NPRED + n) * CDIM;
                float x = row[0], y = row[1], w2 = row[2], h = row[3];
                float* o = outb + pos * 6;
                o[0] = x - w2 * 0.5f;
                o[1] = y - h * 0.5f;
                o[2] = x + w2 * 0.5f;
                o[3] = y + h * 0.5f;
                o[4] = __uint_as_float(hi & 0x7FFFFFFFu);   // score
                o[5] = (float)(key & 0x7Fu);                // class (as float)
            }
        }
    }
}

// ---------------- launch ----------------

extern "C" void kernel_launch(void* const* d_in, const int* in_sizes, int n_in,
                              void* d_out, int out_size, void* d_ws, size_t ws_size,
                              hipStream_t stream) {
    const float* pred = (const float*)d_in[0];
    float* out = (float*)d_out;

    char* ws = (char*)d_ws;
    u64* keys   = (u64*)ws;                                   // 3,670,016 B
    float4* ob  = (float4*)(ws + 3670016);                    // 1,048,576 B
    u8* clsb    = (u8*)(ws + 4718592);                        //    65,536 B
    u16* segIdx = (u16*)(ws + 4784128);                       //   131,072 B
    u32* startg = (u32*)(ws + 4915200);                       //     5,120 B
    u32* count  = (u32*)(ws + 4920320);                       //     5,120 B
    u8* keep    = (u8*)(ws + 4925440);                        //    65,536 B
    u8* gsupp   = (u8*)(ws + 4990976);                        //    65,536 B
    // zero count + keep + gsupp (contiguous): 136,192 B
    (void)hipMemsetAsync(ws + 4920320, 0, 136192, stream);

    hipLaunchKernelGGL(k1_score, dim3(BATCH * NPAD / 16), dim3(256), 0, stream, pred, keys);
    hipLaunchKernelGGL(k2a_sortchunk, dim3(BATCH * NCHUNK), dim3(1024), 0, stream, keys);
    hipLaunchKernelGGL(k2m_merge, dim3(BATCH, 3), dim3(1024), 0, stream, keys, 1);
    hipLaunchKernelGGL(k2m_merge, dim3(BATCH, 2), dim3(1024), 0, stream, keys, 2);
    hipLaunchKernelGGL(k2m_merge, dim3(BATCH, 1), dim3(1024), 0, stream, keys, 4);
    hipLaunchKernelGGL(k3a_build, dim3(BATCH * TOPK / 256), dim3(256), 0, stream,
                       pred, keys, ob, clsb, count);
    hipLaunchKernelGGL(k3g_gather, dim3(BATCH, NCLS), dim3(64), 0, stream,
                       clsb, count, startg, segIdx);
    hipLaunchKernelGGL(k3n_nms, dim3(BATCH, NCLS), dim3(64), 0, stream,
                       ob, segIdx, count, startg, keep, gsupp);
    hipLaunchKernelGGL(k3o_out, dim3(BATCH), dim3(256), 0, stream, pred, keys, keep, out);
}

// Round 5
// 304.605 us; speedup vs baseline: 2.6155x; 1.0361x over previous
//
#include <hip/hip_runtime.h>

#define BATCH  16
#define NPRED  25200
#define NCLS   80
#define CDIM   85
#define TOPK   4096
#define NPAD   28672   // 7 * 4096
#define NCHUNK 7
#define MAXDET 1000
#define CONF_T 0.25f
#define IOU_T  0.45f
#define MAXWH  7680.0f

typedef unsigned long long u64;
typedef unsigned int u32;
typedef unsigned short u16;
typedef unsigned char u8;

__device__ __forceinline__ u64 umax64(u64 a, u64 b) { return a > b ? a : b; }
__device__ __forceinline__ u64 umin64(u64 a, u64 b) { return a < b ? a : b; }

__device__ __forceinline__ void cx_u64(u64* a, int i, int p, bool desc) {
    u64 x = a[i], y = a[p];
    if (desc ? (x < y) : (x > y)) { a[i] = y; a[p] = x; }
}

// ---------------- hybrid bitonic sort: 1024 threads × 4 regs, LDS only for j>=256 ----
// element i = 4*tid + e. j=1,2 in-register; j=4..128 via shfl_xor (partner wave-local);
// j>=256 via LDS pair-index compare-exchange. 10 barrier stages instead of 78.

__device__ void hybrid_sort4096_desc(u64 r[4], u64* a) {
    const int tid = threadIdx.x;
    for (int k = 2; k <= 4096; k <<= 1) {
        if (k >= 512) {                      // LDS stages: j = min(k/2,2048) .. 256
            int jmax = (k >> 1) > 2048 ? 2048 : (k >> 1);
#pragma unroll
            for (int e = 0; e < 4; ++e) a[4 * tid + e] = r[e];
            __syncthreads();
            for (int j = jmax; j >= 256; j >>= 1) {
#pragma unroll
                for (int t2 = 0; t2 < 2; ++t2) {
                    int q = (t2 << 10) | tid;
                    int i = ((q & ~(j - 1)) << 1) | (q & (j - 1));
                    cx_u64(a, i, i | j, (i & k) == 0);
                }
                __syncthreads();
            }
#pragma unroll
            for (int e = 0; e < 4; ++e) r[e] = a[4 * tid + e];
            __syncthreads();                 // protect 'a' before next phase's write
        }
        {                                    // shuffle stages: j = min(k/2,128) .. 4
            int jstart = (k >> 1) > 128 ? 128 : (k >> 1);
            bool desc = (((4 * tid) & k) == 0);
            for (int j = jstart; j >= 4; j >>= 1) {
                int m = j >> 2;
                bool take_max = (((tid & m) == 0) == desc);
#pragma unroll
                for (int e = 0; e < 4; ++e) {
                    u64 v = __shfl_xor(r[e], m, 64);
                    r[e] = take_max ? umax64(r[e], v) : umin64(r[e], v);
                }
            }
        }
        if (k >= 4) {                        // j=2: pairs (0,2),(1,3), dir uniform/thread
            bool desc = (((4 * tid) & k) == 0);
            u64 x0 = r[0], x2 = r[2];
            r[0] = desc ? umax64(x0, x2) : umin64(x0, x2);
            r[2] = desc ? umin64(x0, x2) : umax64(x0, x2);
            u64 x1 = r[1], x3 = r[3];
            r[1] = desc ? umax64(x1, x3) : umin64(x1, x3);
            r[3] = desc ? umin64(x1, x3) : umax64(x1, x3);
        }
        {                                    // j=1: pairs (0,1),(2,3), dir per pair
            bool d01 = (((4 * tid + 0) & k) == 0);
            bool d23 = (((4 * tid + 2) & k) == 0);
            u64 x0 = r[0], x1 = r[1];
            r[0] = d01 ? umax64(x0, x1) : umin64(x0, x1);
            r[1] = d01 ? umin64(x0, x1) : umax64(x0, x1);
            u64 x2 = r[2], x3 = r[3];
            r[2] = d23 ? umax64(x2, x3) : umin64(x2, x3);
            r[3] = d23 ? umin64(x2, x3) : umax64(x2, x3);
        }
    }
}

// desc merge of a bitonic 4096 sequence held in registers (dir uniformly desc)
__device__ void hybrid_merge4096_desc(u64 r[4], u64* a) {
    const int tid = threadIdx.x;
#pragma unroll
    for (int e = 0; e < 4; ++e) a[4 * tid + e] = r[e];
    __syncthreads();
    for (int j = 2048; j >= 256; j >>= 1) {
#pragma unroll
        for (int t2 = 0; t2 < 2; ++t2) {
            int q = (t2 << 10) | tid;
            int i = ((q & ~(j - 1)) << 1) | (q & (j - 1));
            cx_u64(a, i, i | j, true);
        }
        __syncthreads();
    }
#pragma unroll
    for (int e = 0; e < 4; ++e) r[e] = a[4 * tid + e];
    for (int j = 128; j >= 4; j >>= 1) {
        int m = j >> 2;
        bool take_max = ((tid & m) == 0);
#pragma unroll
        for (int e = 0; e < 4; ++e) {
            u64 v = __shfl_xor(r[e], m, 64);
            r[e] = take_max ? umax64(r[e], v) : umin64(r[e], v);
        }
    }
    {   // j=2
        u64 x0 = r[0], x2 = r[2];
        r[0] = umax64(x0, x2); r[2] = umin64(x0, x2);
        u64 x1 = r[1], x3 = r[3];
        r[1] = umax64(x1, x3); r[3] = umin64(x1, x3);
    }
    {   // j=1
        u64 x0 = r[0], x1 = r[1];
        r[0] = umax64(x0, x1); r[1] = umin64(x0, x1);
        u64 x2 = r[2], x3 = r[3];
        r[2] = umax64(x2, x3); r[3] = umin64(x2, x3);
    }
}

// ---------------- K1: score / argmax / key (16 lanes per row, 4 rows per wave) ----------------
// key = ord(score)<<32 | (NPAD-1-n)<<7 | cls   (desc sort == stable argsort(-s))

__global__ __launch_bounds__(256) void k1_score(const float* __restrict__ pred,
                                                u64* __restrict__ keys) {
    const int lane = threadIdx.x & 63;
    const int l16 = lane & 15;
    const long long gw = (long long)blockIdx.x * 4 + (threadIdx.x >> 6);
    const long long rowIdx = gw * 4 + (lane >> 4);       // global row in [0, BATCH*NPAD)
    const int b = (int)(rowIdx / NPAD);
    const int n = (int)(rowIdx - (long long)b * NPAD);
    u64 key = 0ull;
    if (n < NPRED) {
        const float* row = pred + ((long long)b * NPRED + n) * CDIM;
        float obj = row[4];
        u64 m = 0ull;
#pragma unroll
        for (int k = 0; k < 5; ++k) {
            int c = l16 + 16 * k;                        // covers 0..79
            float v = row[5 + c] * obj;                  // reference order: product then max
            u64 mk = ((u64)(__float_as_uint(v) | 0x80000000u) << 32) | (u64)(u32)(NCLS - 1 - c);
            if (mk > m) m = mk;                          // (79-c) low bits: ties pick smaller c
        }
#pragma unroll
        for (int o = 8; o > 0; o >>= 1) {
            u64 other = __shfl_xor(m, o, 64);            // reduce within 16-lane group
            if (other > m) m = other;
        }
        float best = __uint_as_float((u32)(m >> 32) & 0x7FFFFFFFu);
        int cls = (NCLS - 1) - (int)(m & 0x7Fu);
        float s = (best > CONF_T) ? best : -1.0f;
        u32 u = __float_as_uint(s);
        u32 ord = (u & 0x80000000u) ? ~u : (u | 0x80000000u);
        key = ((u64)ord << 32) | ((u64)(u32)(NPAD - 1 - n) << 7) | (u64)(u32)cls;
    }
    if (l16 == 0) keys[(long long)b * NPAD + n] = key;   // padding rows write 0
}

// ---------------- K2a: sort each 4096-chunk (one block per batch×chunk) ----------------

__global__ __launch_bounds__(1024) void k2a_sortchunk(u64* __restrict__ keys) {
    __shared__ u64 a[4096];
    const int tid = threadIdx.x;
    u64* kb = keys + (long long)blockIdx.x * 4096;       // blockIdx.x in [0, BATCH*NCHUNK)
    u64 r[4];
#pragma unroll
    for (int e = 0; e < 4; ++e) r[e] = kb[4 * tid + e];
    hybrid_sort4096_desc(r, a);
#pragma unroll
    for (int e = 0; e < 4; ++e) kb[4 * tid + e] = r[e];
}

// ---------------- K2m: merge chunk pair (c0, c0+stride) -> c0, keep top-4096 ----------------

__global__ __launch_bounds__(1024) void k2m_merge(u64* __restrict__ keys, int stride) {
    __shared__ u64 a[4096];
    const int tid = threadIdx.x;
    const int b = blockIdx.x;
    const int c0 = blockIdx.y * 2 * stride;
    const u64* A = keys + (long long)b * NPAD + (long long)c0 * 4096;
    const u64* B = keys + (long long)b * NPAD + (long long)(c0 + stride) * 4096;
    u64 r[4];
#pragma unroll
    for (int e = 0; e < 4; ++e) {
        int i = 4 * tid + e;
        r[e] = umax64(A[i], B[4095 - i]);   // bitonic sequence holding top-4096 of union
    }
    hybrid_merge4096_desc(r, a);
    u64* O = keys + (long long)b * NPAD + (long long)c0 * 4096;
#pragma unroll
    for (int e = 0; e < 4; ++e) O[4 * tid + e] = r[e];
}

// ---------------- K3a: per-entry class byte + offset-box + class counts ----------------

__global__ __launch_bounds__(256) void k3a_build(const float* __restrict__ pred,
                                                 const u64* __restrict__ keys,
                                                 float4* __restrict__ ob,
                                                 u8* __restrict__ clsb,
                                                 u32* __restrict__ count) {
    const int idx = blockIdx.x * 256 + threadIdx.x;      // 0 .. BATCH*TOPK-1
    const int b = idx >> 12;
    const int r = idx & 4095;
    u64 key = keys[(long long)b * NPAD + r];             // chunk 0 = sorted top-4096
    u32 hi = (u32)(key >> 32);
    u8 c = 0xFF;
    if (hi > 0x80000000u) {                              // score > 0 (valid)
        int n = (NPAD - 1) - (int)((key >> 7) & 0x7FFFu);
        int ci = (int)(key & 0x7Fu);
        const float* row = pred + ((long long)b * NPRED + n) * CDIM;
        float x = row[0], y = row[1], w = row[2], h = row[3];
        float off = (float)ci * MAXWH;
        float4 o;
        o.x = (x - w * 0.5f) + off;
        o.y = (y - h * 0.5f) + off;
        o.z = (x + w * 0.5f) + off;
        o.w = (y + h * 0.5f) + off;
        ob[idx] = o;
        c = (u8)ci;
        atomicAdd(&count[b * NCLS + ci], 1u);
    }
    clsb[idx] = c;
}

// ---------------- K3g: stable per-class index gather (one wave per (b,c)) ----------------

__global__ __launch_bounds__(64) void k3g_gather(const u8* __restrict__ clsb,
                                                 const u32* __restrict__ count,
                                                 u32* __restrict__ startg,
                                                 u16* __restrict__ segIdx) {
    const int b = blockIdx.x;
    const int c = blockIdx.y;
    const int lane = threadIdx.x;
    // start = sum_{c' < c} count[b][c']
    u32 s = (lane < c) ? count[b * NCLS + lane] : 0u;
    if (lane + 64 < c) s += count[b * NCLS + 64 + lane];
#pragma unroll
    for (int o = 32; o > 0; o >>= 1) s += __shfl_xor(s, o, 64);
    if (lane == 0) startg[b * NCLS + c] = s;
    const u32 base = (u32)b * 4096u;
    u32 pos = s;
    const u64 lt = (1ull << lane) - 1ull;
    for (int it = 0; it < 64; ++it) {
        u8 cc = clsb[base + it * 64 + lane];
        u64 m = __ballot(cc == (u8)c);
        if (cc == (u8)c) {
            int ofs = __popcll(m & lt);
            segIdx[base + pos + ofs] = (u16)(it * 64 + lane);
        }
        pos += (u32)__popcll(m);
    }
}

// ---------------- K3n: greedy NMS, one wave per (b,c) ----------------

__global__ __launch_bounds__(64) void k3n_nms(const float4* __restrict__ ob,
                                              const u16* __restrict__ segIdx,
                                              const u32* __restrict__ count,
                                              const u32* __restrict__ startg,
                                              u8* __restrict__ keep,
                                              u8* gsupp_) {
    const int b = blockIdx.x;
    const int c = blockIdx.y;
    const int lane = threadIdx.x;
    const int n = (int)count[b * NCLS + c];
    if (n == 0) return;
    const u32 base = startg[b * NCLS + c];
    __shared__ float4 sbox[1024];
    __shared__ u16 sidx[1024];
    __shared__ u8 ssupp_[1024];
    volatile u8* ssupp = ssupp_;
    volatile u8* gsupp = gsupp_ + b * 4096 + base;       // fallback (n > 1024), pre-zeroed
    const float4* obb = ob + b * 4096;
    const u16* seg = segIdx + b * 4096 + base;

    for (int j = lane; j < n && j < 1024; j += 64) {
        int r = seg[j];
        sidx[j] = (u16)r;
        sbox[j] = obb[r];
        ssupp_[j] = 0;
    }
    __syncthreads();

    {
#pragma clang fp contract(off)
        for (int ii = 0; ii < n; ++ii) {
            bool sup = (ii < 1024) ? (ssupp[ii] != 0) : (gsupp[ii] != 0);
            if (sup) continue;                           // wave-uniform
            int ri = (ii < 1024) ? (int)sidx[ii] : (int)seg[ii];
            if (lane == 0) keep[b * 4096 + ri] = 1;
            float4 bi = (ii < 1024) ? sbox[ii] : obb[seg[ii]];
            float a1 = (bi.z - bi.x) * (bi.w - bi.y);
            for (int jj = ii + 1 + lane; jj < n; jj += 64) {
                float4 bj = (jj < 1024) ? sbox[jj] : obb[seg[jj]];
                float ltx = fmaxf(bi.x, bj.x);
                float lty = fmaxf(bi.y, bj.y);
                float rbx = fminf(bi.z, bj.z);
                float rby = fminf(bi.w, bj.w);
                float ww = fmaxf(rbx - ltx, 0.0f);
                float hh = fmaxf(rby - lty, 0.0f);
                float inter = ww * hh;
                float a2 = (bj.z - bj.x) * (bj.w - bj.y);
                float iou = inter / (((a1 + a2) - inter) + 1e-7f);
                if (iou > IOU_T) {
                    if (jj < 1024) ssupp[jj] = 1; else gsupp[jj] = 1;
                }
            }
            __syncthreads();                             // single-wave: orders LDS supp writes
        }
    }
}

// ---------------- K3o: rank-order compaction + output ----------------

__global__ __launch_bounds__(256) void k3o_out(const float* __restrict__ pred,
                                               const u64* __restrict__ keys,
                                               const u8* __restrict__ keep,
                                               float* __restrict__ out) {
    const int b = blockIdx.x;
    const int tid = threadIdx.x;
    __shared__ u64 words[64];
    __shared__ int wpre[64];
    float* outb = out + (long long)b * MAXDET * 6;
    for (int i = tid; i < MAXDET * 6; i += 256) outb[i] = 0.0f;   // d_out is poisoned
    const u8* kp = keep + b * 4096;
    if (tid < 64) {
        u64 w = 0ull;
        const u64* k8 = (const u64*)(kp + tid * 64);
#pragma unroll
        for (int q = 0; q < 8; ++q) {
            u64 v = k8[q];
#pragma unroll
            for (int bb = 0; bb < 8; ++bb)
                if ((v >> (8 * bb)) & 0xFFull) w |= 1ull << (q * 8 + bb);
        }
        words[tid] = w;
    }
    __syncthreads();
    if (tid == 0) {
        int run = 0;
        for (int t = 0; t < 64; ++t) { wpre[t] = run; run += __popcll(words[t]); }
    }
    __syncthreads();
    const u64* kb = keys + (long long)b * NPAD;
    for (int r = tid; r < 4096; r += 256) {
        int wd = r >> 6;
        if ((words[wd] >> (r & 63)) & 1ull) {
            int pos = wpre[wd] + __popcll(words[wd] & ((1ull << (r & 63)) - 1ull));
            if (pos < MAXDET) {
                u64 key = kb[r];
                u32 hi = (u32)(key >> 32);
                int n = (NPAD - 1) - (int)((key >> 7) & 0x7FFFu);
                const float* row = pred + ((long long)b * NPRED + n) * CDIM;
                float x = row[0], y = row[1], w2 = row[2], h = row[3];
                float* o = outb + pos * 6;
                o[0] = x - w2 * 0.5f;
                o[1] = y - h * 0.5f;
                o[2] = x + w2 * 0.5f;
                o[3] = y + h * 0.5f;
                o[4] = __uint_as_float(hi & 0x7FFFFFFFu);   // score
                o[5] = (float)(key & 0x7Fu);                // class (as float)
            }
        }
    }
}

// ---------------- launch ----------------

extern "C" void kernel_launch(void* const* d_in, const int* in_sizes, int n_in,
                              void* d_out, int out_size, void* d_ws, size_t ws_size,
                              hipStream_t stream) {
    const float* pred = (const float*)d_in[0];
    float* out = (float*)d_out;

    char* ws = (char*)d_ws;
    u64* keys   = (u64*)ws;                                   // 3,670,016 B
    float4* ob  = (float4*)(ws + 3670016);                    // 1,048,576 B
    u8* clsb    = (u8*)(ws + 4718592);                        //    65,536 B
    u16* segIdx = (u16*)(ws + 4784128);                       //   131,072 B
    u32* startg = (u32*)(ws + 4915200);                       //     5,120 B
    u32* count  = (u32*)(ws + 4920320);                       //     5,120 B
    u8* keep    = (u8*)(ws + 4925440);                        //    65,536 B
    u8* gsupp   = (u8*)(ws + 4990976);                        //    65,536 B
    // zero count + keep + gsupp (contiguous): 136,192 B
    (void)hipMemsetAsync(ws + 4920320, 0, 136192, stream);

    hipLaunchKernelGGL(k1_score, dim3(BATCH * NPAD / 16), dim3(256), 0, stream, pred, keys);
    hipLaunchKernelGGL(k2a_sortchunk, dim3(BATCH * NCHUNK), dim3(1024), 0, stream, keys);
    hipLaunchKernelGGL(k2m_merge, dim3(BATCH, 3), dim3(1024), 0, stream, keys, 1);
    hipLaunchKernelGGL(k2m_merge, dim3(BATCH, 2), dim3(1024), 0, stream, keys, 2);
    hipLaunchKernelGGL(k2m_merge, dim3(BATCH, 1), dim3(1024), 0, stream, keys, 4);
    hipLaunchKernelGGL(k3a_build, dim3(BATCH * TOPK / 256), dim3(256), 0, stream,
                       pred, keys, ob, clsb, count);
    hipLaunchKernelGGL(k3g_gather, dim3(BATCH, NCLS), dim3(64), 0, stream,
                       clsb, count, startg, segIdx);
    hipLaunchKernelGGL(k3n_nms, dim3(BATCH, NCLS), dim3(64), 0, stream,
                       ob, segIdx, count, startg, keep, gsupp);
    hipLaunchKernelGGL(k3o_out, dim3(BATCH), dim3(256), 0, stream, pred, keys, keep, out);
}

// Round 7
// 301.098 us; speedup vs baseline: 2.6459x; 1.0116x over previous
//
#include <hip/hip_runtime.h>

#define BATCH  16
#define NPRED  25200
#define NCLS   80
#define CDIM   85
#define TOPK   4096
#define NBUCK  4096
#define MAXDET 1000
#define CONF_T 0.25f
#define IOU_T  0.45f
#define MAXWH  7680.0f
#define ORD_BASE 0xBE800000u   // ord(0.25f); valid score s>0.25 <=> ord > ORD_BASE

typedef unsigned long long u64;
typedef unsigned int u32;
typedef unsigned short u16;
typedef unsigned char u8;

__device__ __forceinline__ u64 umax64(u64 a, u64 b) { return a > b ? a : b; }
__device__ __forceinline__ u64 umin64(u64 a, u64 b) { return a < b ? a : b; }

__device__ __forceinline__ void cx_u64(u64* a, int i, int p, bool desc) {
    u64 x = a[i], y = a[p];
    if (desc ? (x < y) : (x > y)) { a[i] = y; a[p] = x; }
}

// ---------------- hybrid bitonic sort: 1024 threads × 4 regs, LDS only for j>=256 ----

__device__ void hybrid_sort4096_desc(u64 r[4], u64* a) {
    const int tid = threadIdx.x;
    for (int k = 2; k <= 4096; k <<= 1) {
        if (k >= 512) {                      // LDS stages: j = min(k/2,2048) .. 256
            int jmax = (k >> 1) > 2048 ? 2048 : (k >> 1);
#pragma unroll
            for (int e = 0; e < 4; ++e) a[4 * tid + e] = r[e];
            __syncthreads();
            for (int j = jmax; j >= 256; j >>= 1) {
#pragma unroll
                for (int t2 = 0; t2 < 2; ++t2) {
                    int q = (t2 << 10) | tid;
                    int i = ((q & ~(j - 1)) << 1) | (q & (j - 1));
                    cx_u64(a, i, i | j, (i & k) == 0);
                }
                __syncthreads();
            }
#pragma unroll
            for (int e = 0; e < 4; ++e) r[e] = a[4 * tid + e];
            __syncthreads();
        }
        {                                    // shuffle stages: j = min(k/2,128) .. 4
            int jstart = (k >> 1) > 128 ? 128 : (k >> 1);
            bool desc = (((4 * tid) & k) == 0);
            for (int j = jstart; j >= 4; j >>= 1) {
                int m = j >> 2;
                bool take_max = (((tid & m) == 0) == desc);
#pragma unroll
                for (int e = 0; e < 4; ++e) {
                    u64 v = __shfl_xor(r[e], m, 64);
                    r[e] = take_max ? umax64(r[e], v) : umin64(r[e], v);
                }
            }
        }
        if (k >= 4) {                        // j=2
            bool desc = (((4 * tid) & k) == 0);
            u64 x0 = r[0], x2 = r[2];
            r[0] = desc ? umax64(x0, x2) : umin64(x0, x2);
            r[2] = desc ? umin64(x0, x2) : umax64(x0, x2);
            u64 x1 = r[1], x3 = r[3];
            r[1] = desc ? umax64(x1, x3) : umin64(x1, x3);
            r[3] = desc ? umin64(x1, x3) : umax64(x1, x3);
        }
        {                                    // j=1
            bool d01 = (((4 * tid + 0) & k) == 0);
            bool d23 = (((4 * tid + 2) & k) == 0);
            u64 x0 = r[0], x1 = r[1];
            r[0] = d01 ? umax64(x0, x1) : umin64(x0, x1);
            r[1] = d01 ? umin64(x0, x1) : umax64(x0, x1);
            u64 x2 = r[2], x3 = r[3];
            r[2] = d23 ? umax64(x2, x3) : umin64(x2, x3);
            r[3] = d23 ? umin64(x2, x3) : umax64(x2, x3);
        }
    }
}

// full desc sort of 256 u64 held in wave 0 (4 regs/lane), zero barriers
__device__ void wave_sort256_desc(u64 r[4]) {
    const int lane = threadIdx.x & 63;
    for (int k = 2; k <= 256; k <<= 1) {
        int jstart = (k >> 1) > 128 ? 128 : (k >> 1);
        bool desc = (((4 * lane) & k) == 0);
        for (int j = jstart; j >= 4; j >>= 1) {
            int m = j >> 2;
            bool take_max = (((lane & m) == 0) == desc);
#pragma unroll
            for (int e = 0; e < 4; ++e) {
                u64 v = __shfl_xor(r[e], m, 64);
                r[e] = take_max ? umax64(r[e], v) : umin64(r[e], v);
            }
        }
        if (k >= 4) {
            u64 x0 = r[0], x2 = r[2];
            r[0] = desc ? umax64(x0, x2) : umin64(x0, x2);
            r[2] = desc ? umin64(x0, x2) : umax64(x0, x2);
            u64 x1 = r[1], x3 = r[3];
            r[1] = desc ? umax64(x1, x3) : umin64(x1, x3);
            r[3] = desc ? umin64(x1, x3) : umax64(x1, x3);
        }
        {
            bool d01 = (((4 * lane + 0) & k) == 0);
            bool d23 = (((4 * lane + 2) & k) == 0);
            u64 x0 = r[0], x1 = r[1];
            r[0] = d01 ? umax64(x0, x1) : umin64(x0, x1);
            r[1] = d01 ? umin64(x0, x1) : umax64(x0, x1);
            u64 x2 = r[2], x3 = r[3];
            r[2] = d23 ? umax64(x2, x3) : umin64(x2, x3);
            r[3] = d23 ? umin64(x2, x3) : umax64(x2, x3);
        }
    }
}

// ---------------- K1: score / argmax / key / histogram ----------------
// key = ord(score)<<32 | (32767-n)<<7 | cls   (desc sort == stable argsort(-s))

__global__ __launch_bounds__(256) void k1_score(const float* __restrict__ pred,
                                                u64* __restrict__ keys,
                                                u32* __restrict__ ghist) {
    const int lane = threadIdx.x & 63;
    const int l16 = lane & 15;
    const long long gw = (long long)blockIdx.x * 4 + (threadIdx.x >> 6);
    const long long rowIdx = gw * 4 + (lane >> 4);       // global row in [0, BATCH*NPRED)
    const int b = (int)(rowIdx / NPRED);
    const int n = (int)(rowIdx - (long long)b * NPRED);
    const float* row = pred + rowIdx * CDIM;
    float obj = row[4];
    u64 m = 0ull;
#pragma unroll
    for (int k = 0; k < 5; ++k) {
        int c = l16 + 16 * k;                            // covers 0..79
        float v = row[5 + c] * obj;                      // reference order: product then max
        u64 mk = ((u64)(__float_as_uint(v) | 0x80000000u) << 32) | (u64)(u32)(NCLS - 1 - c);
        if (mk > m) m = mk;                              // (79-c) low bits: ties pick smaller c
    }
#pragma unroll
    for (int o = 8; o > 0; o >>= 1) {
        u64 other = __shfl_xor(m, o, 64);                // reduce within 16-lane group
        if (other > m) m = other;
    }
    if (l16 == 0) {
        float best = __uint_as_float((u32)(m >> 32) & 0x7FFFFFFFu);
        int cls = (NCLS - 1) - (int)(m & 0x7Fu);
        float s = (best > CONF_T) ? best : -1.0f;
        u32 u = __float_as_uint(s);
        u32 ord = (u & 0x80000000u) ? ~u : (u | 0x80000000u);
        keys[rowIdx] = ((u64)ord << 32) | ((u64)(u32)(32767 - n) << 7) | (u64)(u32)cls;
        if (ord > ORD_BASE)
            atomicAdd(&ghist[b * NBUCK + ((ord - ORD_BASE - 1u) >> 12)], 1u);
    }
}

// ---------------- K2cs: histogram threshold + compact + sort -> sorted top-4096 ----------------

__global__ __launch_bounds__(1024) void k2cs(const u64* __restrict__ keys,
                                             const u32* __restrict__ ghist,
                                             u64* __restrict__ topSorted) {
    __shared__ u64 smem[4096];          // 32 KB sort arena / compact target
    __shared__ u64 side[1024];          // bucket-T members
    __shared__ u32 wsum[16];
    __shared__ int sh_T, sh_C1, sh_R, c1pos, sidepos;
    const int b = blockIdx.x;
    const int tid = threadIdx.x;
    const int lane = tid & 63;
    const int wid = tid >> 6;

    // --- threshold scan (descending order over buckets) ---
    u32 h[4];
    u32 tsum = 0;
#pragma unroll
    for (int e = 0; e < 4; ++e) {
        h[e] = ghist[b * NBUCK + (NBUCK - 1 - (4 * tid + e))];
        tsum += h[e];
    }
    u32 inc = tsum;
    for (int o = 1; o < 64; o <<= 1) {
        u32 v = __shfl_up(inc, o, 64);
        if (lane >= o) inc += v;
    }
    if (lane == 63) wsum[wid] = inc;
    __syncthreads();
    if (tid == 0) {
        u32 run = 0;
        for (int i = 0; i < 16; ++i) { u32 t = wsum[i]; wsum[i] = run; run += t; }
        sh_T = -1; sh_C1 = (int)run; sh_R = 0;           // defaults: < 4096 valid total
        c1pos = 0; sidepos = 0;
    }
    __syncthreads();
    {
        u32 cum = wsum[wid] + (inc - tsum);              // exclusive prefix before this thread
#pragma unroll
        for (int e = 0; e < 4; ++e) {
            if (h[e] > 0 && cum < (u32)TOPK && cum + h[e] >= (u32)TOPK) {
                sh_T = NBUCK - 1 - (4 * tid + e);        // unique crossing
                sh_C1 = (int)cum;
                sh_R = TOPK - (int)cum;
            }
            cum += h[e];
        }
    }
    __syncthreads();
    const int T = sh_T, C1 = sh_C1, R = sh_R;

    // --- zero arena, compact ---
    for (int i = tid; i < 4096; i += 1024) smem[i] = 0ull;
    side[tid] = 0ull;
    __syncthreads();
    const u64* kb = keys + (long long)b * NPRED;
    for (int n = tid; n < NPRED; n += 1024) {
        u64 key = kb[n];
        u32 hi = (u32)(key >> 32);
        if (hi > ORD_BASE) {
            int bt = (int)((hi - ORD_BASE - 1u) >> 12);
            if (bt > T) {
                int slot = atomicAdd(&c1pos, 1);
                smem[slot] = key;
            } else if (bt == T) {
                int s2 = atomicAdd(&sidepos, 1);
                if (s2 < 1024) side[s2] = key;           // >1024 in one bucket: implausible
            }
        }
    }
    __syncthreads();

    // --- select R largest from bucket T ---
    if (R > 0) {
        int cntT = sidepos;
        if (cntT <= 256) {
            if (wid == 0) {                              // single-wave in-register sort
                u64 r[4];
#pragma unroll
                for (int e = 0; e < 4; ++e) r[e] = side[4 * lane + e];
                wave_sort256_desc(r);
#pragma unroll
                for (int e = 0; e < 4; ++e) side[4 * lane + e] = r[e];
            }
        } else {                                         // rare fallback: block bitonic 1024
            for (int k = 2; k <= 1024; k <<= 1) {
                for (int j = k >> 1; j >= 1; j >>= 1) {
                    if (tid < 512) {
                        int q = tid;
                        int i = ((q & ~(j - 1)) << 1) | (q & (j - 1));
                        cx_u64(side, i, i | j, (i & k) == 0);
                    }
                    __syncthreads();
                }
            }
        }
        __syncthreads();
        if (tid < R) smem[C1 + tid] = side[tid];         // R <= cntT <= 1024
    }
    __syncthreads();

    // --- final full sort of the top-4096 ---
    u64 r[4];
#pragma unroll
    for (int e = 0; e < 4; ++e) r[e] = smem[4 * tid + e];
    hybrid_sort4096_desc(r, smem);
#pragma unroll
    for (int e = 0; e < 4; ++e) topSorted[(long long)b * TOPK + 4 * tid + e] = r[e];
}

// ---------------- K3a: per-entry class byte + offset-box + class counts ----------------

__global__ __launch_bounds__(256) void k3a_build(const float* __restrict__ pred,
                                                 const u64* __restrict__ topSorted,
                                                 float4* __restrict__ ob,
                                                 u8* __restrict__ clsb,
                                                 u32* __restrict__ count) {
    const int idx = blockIdx.x * 256 + threadIdx.x;      // 0 .. BATCH*TOPK-1
    const int b = idx >> 12;
    u64 key = topSorted[idx];
    u32 hi = (u32)(key >> 32);
    u8 c = 0xFF;
    if (hi > 0x80000000u) {                              // score > 0 (valid)
        int n = 32767 - (int)((key >> 7) & 0x7FFFu);
        int ci = (int)(key & 0x7Fu);
        const float* row = pred + ((long long)b * NPRED + n) * CDIM;
        float x = row[0], y = row[1], w = row[2], h = row[3];
        float off = (float)ci * MAXWH;
        float4 o;
        o.x = (x - w * 0.5f) + off;
        o.y = (y - h * 0.5f) + off;
        o.z = (x + w * 0.5f) + off;
        o.w = (y + h * 0.5f) + off;
        ob[idx] = o;
        c = (u8)ci;
        atomicAdd(&count[b * NCLS + ci], 1u);
    }
    clsb[idx] = c;
}

// ---------------- K3g: stable per-class index gather (one wave per (b,c)) ----------------

__global__ __launch_bounds__(64) void k3g_gather(const u8* __restrict__ clsb,
                                                 const u32* __restrict__ count,
                                                 u32* __restrict__ startg,
                                                 u16* __restrict__ segIdx) {
    const int b = blockIdx.x;
    const int c = blockIdx.y;
    const int lane = threadIdx.x;
    // start = sum_{c' < c} count[b][c']  (NCLS=80 > 64: two chunks)
    u32 s = (lane < c) ? count[b * NCLS + lane] : 0u;
    if (lane + 64 < c) s += count[b * NCLS + 64 + lane];
#pragma unroll
    for (int o = 32; o > 0; o >>= 1) s += __shfl_xor(s, o, 64);
    if (lane == 0) startg[b * NCLS + c] = s;
    const u32 base = (u32)b * 4096u;
    u32 pos = s;
    const u64 lt = (1ull << lane) - 1ull;
    for (int it = 0; it < 64; ++it) {
        u8 cc = clsb[base + it * 64 + lane];
        u64 m = __ballot(cc == (u8)c);
        if (cc == (u8)c) {
            int ofs = __popcll(m & lt);
            segIdx[base + pos + ofs] = (u16)(it * 64 + lane);
        }
        pos += (u32)__popcll(m);
    }
}

// ---------------- K3n: greedy NMS, one wave per (b,c) ----------------

__global__ __launch_bounds__(64) void k3n_nms(const float4* __restrict__ ob,
                                              const u16* __restrict__ segIdx,
                                              const u32* __restrict__ count,
                                              const u32* __restrict__ startg,
                                              u8* __restrict__ keep,
                                              u8* gsupp_) {
    const int b = blockIdx.x;
    const int c = blockIdx.y;
    const int lane = threadIdx.x;
    const int n = (int)count[b * NCLS + c];
    if (n == 0) return;
    const u32 base = startg[b * NCLS + c];
    __shared__ float4 sbox[1024];
    __shared__ u16 sidx[1024];
    __shared__ u8 ssupp_[1024];
    volatile u8* ssupp = ssupp_;
    volatile u8* gsupp = gsupp_ + b * 4096 + base;       // fallback (n > 1024), pre-zeroed
    const float4* obb = ob + b * 4096;
    const u16* seg = segIdx + b * 4096 + base;

    for (int j = lane; j < n && j < 1024; j += 64) {
        int r = seg[j];
        sidx[j] = (u16)r;
        sbox[j] = obb[r];
        ssupp_[j] = 0;
    }
    __syncthreads();

    {
#pragma clang fp contract(off)
        for (int ii = 0; ii < n; ++ii) {
            bool sup = (ii < 1024) ? (ssupp[ii] != 0) : (gsupp[ii] != 0);
            if (sup) continue;                           // wave-uniform
            int ri = (ii < 1024) ? (int)sidx[ii] : (int)seg[ii];
            if (lane == 0) keep[b * 4096 + ri] = 1;
            float4 bi = (ii < 1024) ? sbox[ii] : obb[seg[ii]];
            float a1 = (bi.z - bi.x) * (bi.w - bi.y);
            for (int jj = ii + 1 + lane; jj < n; jj += 64) {
                float4 bj = (jj < 1024) ? sbox[jj] : obb[seg[jj]];
                float ltx = fmaxf(bi.x, bj.x);
                float lty = fmaxf(bi.y, bj.y);
                float rbx = fminf(bi.z, bj.z);
                float rby = fminf(bi.w, bj.w);
                float ww = fmaxf(rbx - ltx, 0.0f);
                float hh = fmaxf(rby - lty, 0.0f);
                float inter = ww * hh;
                float a2 = (bj.z - bj.x) * (bj.w - bj.y);
                float iou = inter / (((a1 + a2) - inter) + 1e-7f);
                if (iou > IOU_T) {
                    if (jj < 1024) ssupp[jj] = 1; else gsupp[jj] = 1;
                }
            }
            __syncthreads();                             // single-wave: orders LDS supp writes
        }
    }
}

// ---------------- K3o: rank-order compaction + output ----------------

__global__ __launch_bounds__(256) void k3o_out(const float* __restrict__ pred,
                                               const u64* __restrict__ topSorted,
                                               const u8* __restrict__ keep,
                                               float* __restrict__ out) {
    const int b = blockIdx.x;
    const int tid = threadIdx.x;
    __shared__ u64 words[64];
    __shared__ int wpre[64];
    float* outb = out + (long long)b * MAXDET * 6;
    for (int i = tid; i < MAXDET * 6; i += 256) outb[i] = 0.0f;   // d_out is poisoned
    const u8* kp = keep + b * 4096;
    if (tid < 64) {
        u64 w = 0ull;
        const u64* k8 = (const u64*)(kp + tid * 64);
#pragma unroll
        for (int q = 0; q < 8; ++q) {
            u64 v = k8[q];
#pragma unroll
            for (int bb = 0; bb < 8; ++bb)
                if ((v >> (8 * bb)) & 0xFFull) w |= 1ull << (q * 8 + bb);
        }
        words[tid] = w;
    }
    __syncthreads();
    if (tid == 0) {
        int run = 0;
        for (int t = 0; t < 64; ++t) { wpre[t] = run; run += __popcll(words[t]); }
    }
    __syncthreads();
    const u64* kb = topSorted + (long long)b * TOPK;
    for (int r = tid; r < 4096; r += 256) {
        int wd = r >> 6;
        if ((words[wd] >> (r & 63)) & 1ull) {
            int pos = wpre[wd] + __popcll(words[wd] & ((1ull << (r & 63)) - 1ull));
            if (pos < MAXDET) {
                u64 key = kb[r];
                u32 hi = (u32)(key >> 32);
                int n = 32767 - (int)((key >> 7) & 0x7FFFu);
                const float* row = pred + ((long long)b * NPRED + n) * CDIM;
                float x = row[0], y = row[1], w2 = row[2], h = row[3];
                float* o = outb + pos * 6;
                o[0] = x - w2 * 0.5f;
                o[1] = y - h * 0.5f;
                o[2] = x + w2 * 0.5f;
                o[3] = y + h * 0.5f;
                o[4] = __uint_as_float(hi & 0x7FFFFFFFu);   // score
                o[5] = (float)(key & 0x7Fu);                // class (as float)
            }
        }
    }
}

// ---------------- launch ----------------

extern "C" void kernel_launch(void* const* d_in, const int* in_sizes, int n_in,
                              void* d_out, int out_size, void* d_ws, size_t ws_size,
                              hipStream_t stream) {
    const float* pred = (const float*)d_in[0];
    float* out = (float*)d_out;

    char* ws = (char*)d_ws;
    u64* keys      = (u64*)ws;                            // 16*25200*8 = 3,225,600 B
    u64* topSorted = (u64*)(ws + 3225600);                // 16*4096*8  =   524,288 B
    float4* ob     = (float4*)(ws + 3749888);             // 16*4096*16 = 1,048,576 B
    u8* clsb       = (u8*)(ws + 4798464);                 //    65,536 B
    u16* segIdx    = (u16*)(ws + 4864000);                //   131,072 B
    u32* startg    = (u32*)(ws + 4995072);                //     5,120 B
    u32* ghist     = (u32*)(ws + 5000192);                //   262,144 B  [zeroed]
    u32* count     = (u32*)(ws + 5262336);                //     5,120 B  [zeroed]
    u8* keep       = (u8*)(ws + 5267456);                 //    65,536 B  [zeroed]
    u8* gsupp      = (u8*)(ws + 5332992);                 //    65,536 B  [zeroed]
    (void)hipMemsetAsync(ws + 5000192, 0, 398336, stream);

    hipLaunchKernelGGL(k1_score, dim3(BATCH * NPRED / 16), dim3(256), 0, stream,
                       pred, keys, ghist);
    hipLaunchKernelGGL(k2cs, dim3(BATCH), dim3(1024), 0, stream, keys, ghist, topSorted);
    hipLaunchKernelGGL(k3a_build, dim3(BATCH * TOPK / 256), dim3(256), 0, stream,
                       pred, topSorted, ob, clsb, count);
    hipLaunchKernelGGL(k3g_gather, dim3(BATCH, NCLS), dim3(64), 0, stream,
                       clsb, count, startg, segIdx);
    hipLaunchKernelGGL(k3n_nms, dim3(BATCH, NCLS), dim3(64), 0, stream,
                       ob, segIdx, count, startg, keep, gsupp);
    hipLaunchKernelGGL(k3o_out, dim3(BATCH), dim3(256), 0, stream, pred, topSorted, keep, out);
}